// Round 4
// baseline (301.299 us; speedup 1.0000x reference)
//
#include <hip/hip_runtime.h>

#define B_   16
#define CIN  32
#define COUT 32
#define HH   256
#define WW   256
#define NE   8
#define NTAP 9
#define KTOT (NTAP * CIN)   // 288

#define TH 8
#define TW 32
#define LROWS (TH + 2)      // 10
#define LCOLS (TW + 2)      // 34
#define PXS   40            // ushorts per pixel: 32 data + 8 pad (80 B stride)
#define NG    10            // aligned float4 column-groups per row

typedef __attribute__((ext_vector_type(8))) short  short8;   // 8 bf16 = 4 VGPRs
typedef __attribute__((ext_vector_type(4))) float  floatx4;  // MFMA C/D

__device__ __forceinline__ unsigned short f2bf(float f) {
    unsigned int u = __float_as_uint(f);
    u += 0x7FFFu + ((u >> 16) & 1u);
    return (unsigned short)(u >> 16);
}

// ---------------------------------------------------------------------------
// Mix expert weights -> bf16 [b][co][k = tap*32 + ci]; bias fp32 [b][co].
// 577 blocks: 576 weight blocks (1 elem/thread), block 576 does ALL 512 bias
// entries via a strided loop (bugfix: 512 > 256 threads).
// Reference weight flat index: co*288 + ci*9 + tap.
// ---------------------------------------------------------------------------
__global__ __launch_bounds__(256) void prep_weights(
    const float* __restrict__ routing,   // [16][8]
    const float* __restrict__ ew,        // [8][9216]
    const float* __restrict__ eb,        // [8][32]
    unsigned short* __restrict__ ws_w,   // [16][32][288] bf16 bits
    float* __restrict__ ws_b)            // [16][32]
{
    const int t = threadIdx.x;
    if (blockIdx.x < 576) {
        const int gidx = blockIdx.x * 256 + t;       // < 16*32*288 = 147456
        const int b    = gidx / (COUT * KTOT);
        const int rem  = gidx - b * (COUT * KTOT);
        const int co   = rem / KTOT;
        const int k    = rem - co * KTOT;
        const int tap  = k >> 5;
        const int ci   = k & 31;
        float acc = 0.f;
#pragma unroll
        for (int e = 0; e < NE; ++e)
            acc += routing[b * NE + e] *
                   ew[e * (COUT * CIN * 9) + co * (CIN * 9) + ci * 9 + tap];
        ws_w[gidx] = f2bf(acc);
    } else {
        for (int i = t; i < B_ * COUT; i += 256) {   // all 512 entries
            const int b  = i >> 5;
            const int co = i & 31;
            float acc = 0.f;
#pragma unroll
            for (int e = 0; e < NE; ++e)
                acc += routing[b * NE + e] * eb[e * COUT + co];
            ws_b[i] = acc;
        }
    }
}

// ---------------------------------------------------------------------------
// Implicit-GEMM conv. Block = 256 thr (4 waves), 8x32 output tile, one batch.
// LDS 27.2 KB -> 4 blocks/CU with __launch_bounds__(256,4).
// Staging: aligned float4 x 8 planes per task (4 pixels), fused fp32->bf16,
// LDS layout [pixel][ci]. Single barrier, then 9-tap K loop on MFMA.
// ---------------------------------------------------------------------------
__global__ __launch_bounds__(256, 4) void condconv_mfma(
    const float* __restrict__ x,             // [16][32][256][256] fp32
    const unsigned short* __restrict__ wsw,  // [16][32][288] bf16
    const float* __restrict__ wsb,           // [16][32]
    float* __restrict__ out)                 // [16][32][256][256] fp32
{
    __shared__ __align__(16) unsigned short s_x[LROWS * LCOLS * PXS];  // 27200 B

    const int b    = blockIdx.z;
    const int x0   = blockIdx.x * TW;
    const int y0   = blockIdx.y * TH;
    const int t    = threadIdx.x;
    const int lane = t & 63;
    const int wv   = t >> 6;        // wave 0..3
    const int ln   = lane & 15;
    const int quad = lane >> 4;

    // --- stage input tile: fp32 NCHW -> bf16 [pixel][ci] LDS ---
    // task = (row*NG + g)*4 + c : 4 pixels (aligned float4) x 8 planes
    for (int task = t; task < LROWS * NG * 4; task += 256) {
        const int c   = task & 3;
        const int p   = task >> 2;
        const int row = p / NG;
        const int g   = p - row * NG;
        const int gy  = y0 + row - 1;
        const int gx0 = x0 + 4 * g - 4;          // 16B-aligned
        const bool iny = (gy >= 0) && (gy < HH);
        if (iny && gx0 >= 0 && gx0 + 3 < WW) {
            const float* src = x + (((size_t)(b * CIN + c * 8)) * HH + gy) * WW + gx0;
            float4 v[8];
#pragma unroll
            for (int u = 0; u < 8; ++u)
                v[u] = *(const float4*)(src + (size_t)u * HH * WW);
#pragma unroll
            for (int j = 0; j < 4; ++j) {
                const int col = 4 * g - 3 + j;
                if (col >= 0 && col < LCOLS) {
                    short8 pk;
#pragma unroll
                    for (int u = 0; u < 8; ++u)
                        pk[u] = (short)f2bf(((const float*)&v[u])[j]);
                    *(short8*)&s_x[(row * LCOLS + col) * PXS + c * 8] = pk;
                }
            }
        } else {
            // edge path: per-pixel, zero-fill OOB
#pragma unroll
            for (int j = 0; j < 4; ++j) {
                const int col = 4 * g - 3 + j;
                if (col >= 0 && col < LCOLS) {
                    const int gx = gx0 + j;
                    short8 pk;
                    if (iny && gx >= 0 && gx < WW) {
                        const float* src = x + (((size_t)(b * CIN + c * 8)) * HH + gy) * WW + gx;
#pragma unroll
                        for (int u = 0; u < 8; ++u)
                            pk[u] = (short)f2bf(src[(size_t)u * HH * WW]);
                    } else {
#pragma unroll
                        for (int u = 0; u < 8; ++u) pk[u] = 0;
                    }
                    *(short8*)&s_x[(row * LCOLS + col) * PXS + c * 8] = pk;
                }
            }
        }
    }

    // --- preload A fragments (weights) + bias (L2-resident, hides in barrier) ---
    short8 afrag[NTAP][2];
    {
        const unsigned short* wb = wsw + (size_t)b * COUT * KTOT;
#pragma unroll
        for (int tap = 0; tap < NTAP; ++tap)
#pragma unroll
            for (int h = 0; h < 2; ++h)
                afrag[tap][h] = *(const short8*)(wb + (h * 16 + ln) * KTOT + tap * 32 + quad * 8);
    }
    float bias_v[2][4];
#pragma unroll
    for (int h = 0; h < 2; ++h)
#pragma unroll
        for (int rg = 0; rg < 4; ++rg)
            bias_v[h][rg] = wsb[b * COUT + h * 16 + quad * 4 + rg];

    __syncthreads();

    // --- K loop: 9 taps x 4 px-tiles x 2 co-halves ---
    floatx4 acc[4][2];
#pragma unroll
    for (int tt = 0; tt < 4; ++tt)
#pragma unroll
        for (int h = 0; h < 2; ++h)
            acc[tt][h] = (floatx4){0.f, 0.f, 0.f, 0.f};

#pragma unroll
    for (int tap = 0; tap < NTAP; ++tap) {
        const int dy = tap / 3;
        const int dx = tap - dy * 3;
#pragma unroll
        for (int tt = 0; tt < 4; ++tt) {
            const int r    = 2 * wv + (tt >> 1);
            const int q    = tt & 1;
            const int lrow = r + dy;
            const int lcol = q * 16 + ln + dx;
            const short8 bfr = *(const short8*)&s_x[(lrow * LCOLS + lcol) * PXS + quad * 8];
            acc[tt][0] = __builtin_amdgcn_mfma_f32_16x16x32_bf16(afrag[tap][0], bfr, acc[tt][0], 0, 0, 0);
            acc[tt][1] = __builtin_amdgcn_mfma_f32_16x16x32_bf16(afrag[tap][1], bfr, acc[tt][1], 0, 0, 0);
        }
    }

    // --- epilogue: bias + coalesced stores ---
#pragma unroll
    for (int tt = 0; tt < 4; ++tt) {
        const int r  = 2 * wv + (tt >> 1);
        const int q  = tt & 1;
        const int gy = y0 + r;
        const int gx = x0 + q * 16 + ln;
#pragma unroll
        for (int h = 0; h < 2; ++h)
#pragma unroll
            for (int rg = 0; rg < 4; ++rg) {
                const int co = h * 16 + quad * 4 + rg;
                out[(((size_t)b * COUT + co) * HH + gy) * WW + gx] = acc[tt][h][rg] + bias_v[h][rg];
            }
    }
}

extern "C" void kernel_launch(void* const* d_in, const int* in_sizes, int n_in,
                              void* d_out, int out_size, void* d_ws, size_t ws_size,
                              hipStream_t stream) {
    const float* x       = (const float*)d_in[0];
    const float* routing = (const float*)d_in[1];
    const float* ew      = (const float*)d_in[2];
    const float* eb      = (const float*)d_in[3];
    float* out = (float*)d_out;

    unsigned short* ws_w = (unsigned short*)d_ws;            // 294912 B
    float* ws_b = (float*)((char*)d_ws + (size_t)B_ * COUT * KTOT * 2);

    prep_weights<<<dim3(577), dim3(256), 0, stream>>>(routing, ew, eb, ws_w, ws_b);

    dim3 grid(WW / TW, HH / TH, B_);                         // (8, 32, 16)
    condconv_mfma<<<grid, dim3(256), 0, stream>>>(x, ws_w, ws_b, out);
}